// Round 13
// baseline (43.012 us; speedup 1.0000x reference)
//
#include <hip/hip_runtime.h>
#include <hip/hip_bf16.h>

#define BB 16
#define NN 16384
#define DD 128
#define CC 32
#define CHUNKS 16
#define NBLK (BB * CHUNKS)                  // 256
#define ROWS_PER_BLOCK (NN / CHUNKS)        // 1024

// ---- PATH A workspace layout (floats) ----
#define P_SUMS 0                                    // NBLK*4096 (4.2 MB)
#define P_CNTS ((size_t)NBLK * CC * DD)             // NBLK*32
#define LOSSP  (P_CNTS + (size_t)NBLK * CC)         // BB
#define GCTR   (LOSSP + BB)                         // 1 int
#define WS_A_FLOATS (GCTR + 1)

typedef __attribute__((address_space(1))) const unsigned int glb_u32;
typedef __attribute__((address_space(3))) unsigned int lds_u32;

// ---------------- Kernel 1: segment sums via global_load_lds DMA ------------
// 256 blocks x 512 thr (8 waves; 1 block/CU). Wave (rr,h): 256 rows x 64-col
// half; slab 8 KB (proven engine). NEW: x is streamed by direct-to-LDS DMA
// (dwordx4, 1 KB/instr/wave) into a 4-slot ring, 3 groups (6 DMAs, 6 KB/wave)
// in flight via counted asm vmcnt (T4) — consume path fully decoupled from
// VGPR load-return. Same per-column fp order as R12 -> absmax 0.0.
__global__ __launch_bounds__(512) void seg_sum_kernel(
    const float* __restrict__ x, const int* __restrict__ ids,
    float* __restrict__ outsums, float* __restrict__ outcnts,
    int* __restrict__ gctr) {
  __shared__ float slab[8][CC * 64];      // 64 KB
  __shared__ float stage[8][4][512];      // 64 KB: 8 waves x 4 slots x 8x64
  __shared__ float lcnt[CC];
  __shared__ int   lcid[ROWS_PER_BLOCK];  // 4 KB

  const int tid  = threadIdx.x;
  const int b    = blockIdx.y;
  const int row0 = blockIdx.x * ROWS_PER_BLOCK;
  const int lane = tid & 63;
  const int w    = tid >> 6;              // wave 0..7
  const int rr   = w >> 1;                // row-quarter (256 rows)
  const int h    = w & 1;                 // col-half
  const int slot = b * CHUNKS + blockIdx.x;
  const int* __restrict__ idrow = ids + (size_t)b * NN;

  if (tid < CC) lcnt[tid] = 0.f;
  lcid[tid]       = idrow[row0 + tid];
  lcid[tid + 512] = idrow[row0 + tid + 512];
  {
    const float4 z4 = make_float4(0.f, 0.f, 0.f, 0.f);
#pragma unroll
    for (int i = 0; i < 8; ++i)
      *reinterpret_cast<float4*>(&slab[w][(i * 64 + lane) * 4]) = z4;
  }
  __syncthreads();
  atomicAdd(&lcnt[lcid[tid]], 1.f);
  atomicAdd(&lcnt[lcid[tid + 512]], 1.f);
  __syncthreads();   // drains vmcnt/lgkmcnt: ring starts with 0 outstanding

  // DMA source for this lane: row = row0 + rr*256 + (lane>>4) (+ group offs),
  // col = h*64 + (lane&15)*4. LDS dest is wave-uniform; HW adds lane*16B, so
  // staged layout = [8 half-rows][64 cols] contiguous: row j at j*64.
  const float* gsrc = x + ((size_t)b * NN + row0 + rr * 256 + (lane >> 4)) * DD
                        + h * 64 + (lane & 15) * 4;
  float* const sl = &slab[w][0];
  const int kb0 = rr * 256;

#define ISSUE(g)                                                            \
  {                                                                         \
    asm volatile("s_waitcnt lgkmcnt(0)" ::: "memory");                      \
    __builtin_amdgcn_global_load_lds(                                       \
        (glb_u32*)(gsrc + ((g) * 8 + 0) * DD),                              \
        (lds_u32*)&stage[w][(g) & 3][0], 16, 0, 0);                         \
    __builtin_amdgcn_global_load_lds(                                       \
        (glb_u32*)(gsrc + ((g) * 8 + 4) * DD),                              \
        (lds_u32*)&stage[w][(g) & 3][256], 16, 0, 0);                       \
  }
#define CONSUME(g)                                                          \
  {                                                                         \
    _Pragma("unroll") for (int j = 0; j < 8; ++j) {                         \
      const float v = stage[w][(g) & 3][j * 64 + lane];                     \
      const int cid = lcid[kb0 + (g) * 8 + j];                              \
      float* p = &sl[cid * 64 + lane];                                      \
      *p = *p + v;                                                          \
    }                                                                       \
  }

  ISSUE(0) ISSUE(1) ISSUE(2)
  for (int g = 0; g < 29; ++g) {          // 32 groups of 8 rows
    ISSUE(g + 3)
    asm volatile("s_waitcnt vmcnt(6)" ::: "memory");
    __builtin_amdgcn_sched_barrier(0);
    CONSUME(g)
  }
  asm volatile("s_waitcnt vmcnt(4)" ::: "memory");
  __builtin_amdgcn_sched_barrier(0);
  CONSUME(29)
  asm volatile("s_waitcnt vmcnt(2)" ::: "memory");
  __builtin_amdgcn_sched_barrier(0);
  CONSUME(30)
  asm volatile("s_waitcnt vmcnt(0)" ::: "memory");
  __builtin_amdgcn_sched_barrier(0);
  CONSUME(31)
#undef ISSUE
#undef CONSUME
  __syncthreads();

  // epilogue: fold 4 row-quarters per col-half, plain-store 16 KB partial
  float* __restrict__ ps = outsums + (size_t)slot * CC * DD;
#pragma unroll
  for (int it = 0; it < 8; ++it) {
    const int idx = it * 512 + tid;       // c*128 + h2*64 + j
    const int c  = idx >> 7;
    const int r  = idx & 127;
    const int h2 = r >> 6;
    const int j  = r & 63;
    const int o  = c * 64 + j;
    ps[idx] = slab[h2][o] + slab[2 + h2][o] + slab[4 + h2][o] + slab[6 + h2][o];
  }
  if (tid < CC) outcnts[slot * CC + tid] = lcnt[tid];
  if (slot == 0 && tid == 0)
    __hip_atomic_store(gctr, 0, __ATOMIC_RELAXED, __HIP_MEMORY_SCOPE_AGENT);
}

// ---------------- Kernel 2: fused reduce + gram + final (proven) ------------
#define MSTR 132
__global__ __launch_bounds__(512) void finish_fused_kernel(
    const float* __restrict__ psums, const float* __restrict__ pcnts,
    float* __restrict__ lossp, int* __restrict__ gctr,
    float* __restrict__ out) {
  __shared__ float mean[CC * MSTR];
  __shared__ float cnt[CC];
  __shared__ float red[512];

  const int b = blockIdx.x;
  const int tid = threadIdx.x;

  if (tid < CC) {
    float cs = 0.f;
#pragma unroll
    for (int c = 0; c < CHUNKS; ++c) cs += pcnts[(b * CHUNKS + c) * CC + tid];
    cnt[tid] = cs;
  }

  float4 a0 = make_float4(0.f, 0.f, 0.f, 0.f), a1 = a0;
  const size_t base = (size_t)b * CHUNKS * CC * DD + (size_t)tid * 8;
#pragma unroll 4
  for (int c = 0; c < CHUNKS; ++c) {
    const float4* p = reinterpret_cast<const float4*>(&psums[base + (size_t)c * CC * DD]);
    float4 q0 = p[0], q1 = p[1];
    a0.x += q0.x; a0.y += q0.y; a0.z += q0.z; a0.w += q0.w;
    a1.x += q1.x; a1.y += q1.y; a1.z += q1.z; a1.w += q1.w;
  }
  __syncthreads();

  {
    const int c = tid >> 4;
    const int d0 = (tid & 15) * 8;
    const float inv = 1.f / fmaxf(cnt[c], 1.f);
    float* mrow = &mean[c * MSTR + d0];
    mrow[0] = a0.x * inv; mrow[1] = a0.y * inv; mrow[2] = a0.z * inv; mrow[3] = a0.w * inv;
    mrow[4] = a1.x * inv; mrow[5] = a1.y * inv; mrow[6] = a1.z * inv; mrow[7] = a1.w * inv;
  }
  __syncthreads();

  float acc = 0.f;
  if (tid < (CC * (CC - 1)) / 2) {
    int c = 0, rem = tid;
    while (rem >= (CC - 1 - c)) { rem -= (CC - 1 - c); ++c; }
    int e = c + 1 + rem;
    const float4* mc = reinterpret_cast<const float4*>(&mean[c * MSTR]);
    const float4* me = reinterpret_cast<const float4*>(&mean[e * MSTR]);
    float dot = 0.f;
#pragma unroll 8
    for (int j = 0; j < DD / 4; ++j) {
      float4 u = mc[j], v = me[j];
      dot += u.x * v.x + u.y * v.y + u.z * v.z + u.w * v.w;
    }
    acc = fabsf(dot);
  }

  red[tid] = acc;
  __syncthreads();
  for (int s = 256; s > 0; s >>= 1) {
    if (tid < s) red[tid] += red[tid + s];
    __syncthreads();
  }

  if (tid == 0) {
    float valid = 0.f;
    for (int c = 0; c < CC; ++c) valid += (cnt[c] > 0.f) ? 1.f : 0.f;
    float denom = (valid > 1.f) ? valid * (valid - 1.f) * 0.5f : 1.f;
    float v = red[0] / denom * (1.0f / BB);
    __hip_atomic_store(&lossp[b], v, __ATOMIC_RELAXED, __HIP_MEMORY_SCOPE_AGENT);
    __threadfence();
    int old = __hip_atomic_fetch_add(gctr, 1, __ATOMIC_ACQ_REL,
                                     __HIP_MEMORY_SCOPE_AGENT);
    if (old == BB - 1) {
      __threadfence();
      float s = 0.f;
#pragma unroll
      for (int i = 0; i < BB; ++i)
        s += __hip_atomic_load(&lossp[i], __ATOMIC_RELAXED,
                               __HIP_MEMORY_SCOPE_AGENT);
      out[0] = s;
    }
  }
}

// ---------------- PATH B fallback (atomic accumulate) -----------------------
#define RPB_B 512
#define ROWS_PER_WAVE_B 128
__global__ __launch_bounds__(256) void seg_sum_rmw_b(
    const float* __restrict__ x, const int* __restrict__ ids,
    float* __restrict__ gsums, float* __restrict__ gcounts) {
  __shared__ float lsum[4][CC * DD];
  __shared__ float lcnt[CC];
  __shared__ int   lcid[RPB_B];

  const int tid  = threadIdx.x;
  const int b    = blockIdx.y;
  const int row0 = blockIdx.x * RPB_B;
  const int lane = tid & 63;
  const int w    = tid >> 6;
  const int* __restrict__ idrow = ids + (size_t)b * NN;

  if (tid < CC) lcnt[tid] = 0.f;
  lcid[tid]       = idrow[row0 + tid];
  lcid[tid + 256] = idrow[row0 + tid + 256];
  {
    const float4 z4 = make_float4(0.f, 0.f, 0.f, 0.f);
#pragma unroll
    for (int i = 0; i < 16; ++i)
      *reinterpret_cast<float4*>(&lsum[w][(i * 64 + lane) * 4]) = z4;
  }
  __syncthreads();
  atomicAdd(&lcnt[lcid[tid]], 1.f);
  atomicAdd(&lcnt[lcid[tid + 256]], 1.f);

  const float2* __restrict__ x2 =
      reinterpret_cast<const float2*>(x + (size_t)b * NN * DD);
  const int wbase = w * ROWS_PER_WAVE_B;
  float* const slab = &lsum[w][0];

  for (int g = 0; g < ROWS_PER_WAVE_B / 8; ++g) {
    float2 v[8]; int cid[8];
#pragma unroll
    for (int k = 0; k < 8; ++k) {
      const int rl = wbase + g * 8 + k;
      v[k]   = x2[(size_t)(row0 + rl) * 64 + lane];
      cid[k] = lcid[rl];
    }
#pragma unroll
    for (int k = 0; k < 8; ++k) {
      float2* p = reinterpret_cast<float2*>(&slab[cid[k] * DD + 2 * lane]);
      float2 old = *p;
      *p = make_float2(old.x + v[k].x, old.y + v[k].y);
    }
  }
  __syncthreads();

  float* __restrict__ gs = gsums + (size_t)b * CC * DD;
  for (int i = tid; i < CC * DD; i += 256) {
    float s = lsum[0][i] + lsum[1][i] + lsum[2][i] + lsum[3][i];
    atomicAdd(&gs[i], s);
  }
  if (tid < CC) atomicAdd(&gcounts[b * CC + tid], lcnt[tid]);
}

__global__ __launch_bounds__(512) void finish_kernel_b(
    const float* __restrict__ gsums, const float* __restrict__ gcounts,
    float* __restrict__ out) {
  __shared__ float mean[CC * MSTR];
  __shared__ float cnt[CC];
  __shared__ float red[512];

  const int b = blockIdx.x;
  const int tid = threadIdx.x;

  if (tid < CC) cnt[tid] = gcounts[b * CC + tid];
  __syncthreads();
  for (int i = tid; i < CC * DD; i += 512) {
    int c = i >> 7;
    int d = i & 127;
    mean[c * MSTR + d] = gsums[(size_t)b * CC * DD + i] / fmaxf(cnt[c], 1.f);
  }
  __syncthreads();

  float acc = 0.f;
  if (tid < (CC * (CC - 1)) / 2) {
    int c = 0, rem = tid;
    while (rem >= (CC - 1 - c)) { rem -= (CC - 1 - c); ++c; }
    int e = c + 1 + rem;
    const float4* mc = reinterpret_cast<const float4*>(&mean[c * MSTR]);
    const float4* me = reinterpret_cast<const float4*>(&mean[e * MSTR]);
    float dot = 0.f;
#pragma unroll 8
    for (int jj = 0; jj < DD / 4; ++jj) {
      float4 u = mc[jj], v = me[jj];
      dot += u.x * v.x + u.y * v.y + u.z * v.z + u.w * v.w;
    }
    acc = fabsf(dot);
  }
  red[tid] = acc;
  __syncthreads();
  for (int s = 256; s > 0; s >>= 1) {
    if (tid < s) red[tid] += red[tid + s];
    __syncthreads();
  }
  if (tid == 0) {
    float valid = 0.f;
    for (int c = 0; c < CC; ++c) valid += (cnt[c] > 0.f) ? 1.f : 0.f;
    float denom = (valid > 1.f) ? valid * (valid - 1.f) * 0.5f : 1.f;
    atomicAdd(out, red[0] / denom * (1.0f / BB));
  }
}

extern "C" void kernel_launch(void* const* d_in, const int* in_sizes, int n_in,
                              void* d_out, int out_size, void* d_ws, size_t ws_size,
                              hipStream_t stream) {
  const float* x   = (const float*)d_in[0];
  const int*   ids = (const int*)d_in[1];
  float* out = (float*)d_out;
  float* ws  = (float*)d_ws;

  if (ws_size >= WS_A_FLOATS * sizeof(float)) {
    float* psums = ws + P_SUMS;
    float* pcnts = ws + P_CNTS;
    float* lossp = ws + LOSSP;
    int*   gctr  = (int*)(ws + GCTR);
    dim3 grid1(CHUNKS, BB);
    seg_sum_kernel<<<grid1, 512, 0, stream>>>(x, ids, psums, pcnts, gctr);
    finish_fused_kernel<<<BB, 512, 0, stream>>>(psums, pcnts, lossp, gctr, out);
  } else {
    float* gsums   = ws;
    float* gcounts = gsums + (size_t)BB * CC * DD;
    const size_t wsb = ((size_t)BB * CC * DD + (size_t)BB * CC) * sizeof(float);
    hipMemsetAsync(d_ws, 0, wsb, stream);
    hipMemsetAsync(d_out, 0, sizeof(float), stream);
    dim3 gridb(NN / RPB_B, BB);
    seg_sum_rmw_b<<<gridb, 256, 0, stream>>>(x, ids, gsums, gcounts);
    finish_kernel_b<<<BB, 512, 0, stream>>>(gsums, gcounts, out);
  }
}

// Round 15
// 36.488 us; speedup vs baseline: 1.1788x; 1.1788x over previous
//
#include <hip/hip_runtime.h>
#include <hip/hip_bf16.h>

#define BB 16
#define NN 16384
#define DD 128
#define CC 32
#define CHUNKS 16
#define NBLK (BB * CHUNKS)                  // 256
#define ROWS_PER_BLOCK (NN / CHUNKS)        // 1024

// ---- PATH A workspace layout (floats) ----
#define P_SUMS 0                                    // NBLK*4096 (4.2 MB)
#define P_CNTS ((size_t)NBLK * CC * DD)             // NBLK*32
#define LOSSP  (P_CNTS + (size_t)NBLK * CC)         // BB
#define GCTR   (LOSSP + BB)                         // 1 int
#define WS_A_FLOATS (GCTR + 1)

// ---------------- Kernel 1: segment sums (float4 loads, permuted RMW) -------
// Single-variable A/B vs R12: load width 4B -> 16B/lane. 256 blocks x 512 thr
// (8 waves, 1 block/CU — R12 proved this occupancy ties). Wave w owns 128
// rows; each float4 instr reads 2 full rows (1 KB contiguous = m13's copy
// shape). RMW into per-wave 16 KB slab at PERMUTED d-index perm(4m+j)=j*32+m
// (R0/R1 trick): each of the 4 scalar DS ops is 2-way-bank-free. Permutation
// is cluster-uniform -> cancels in the gram (sums over d). Counts exact.
__global__ __launch_bounds__(512) void seg_sum_kernel(
    const float* __restrict__ x, const int* __restrict__ ids,
    float* __restrict__ outsums, float* __restrict__ outcnts,
    int* __restrict__ gctr) {
  __shared__ float slab[8][CC * DD];      // 128 KB
  __shared__ float lcnt[CC];
  __shared__ int   lcid[ROWS_PER_BLOCK];  // 4 KB

  const int tid  = threadIdx.x;
  const int b    = blockIdx.y;
  const int row0 = blockIdx.x * ROWS_PER_BLOCK;
  const int lane = tid & 63;
  const int w    = tid >> 6;              // wave 0..7, owns 128 rows
  const int pr   = lane >> 5;             // row parity within instr
  const int m    = lane & 31;             // lane-in-row (covers 4 d)
  const int slot = b * CHUNKS + blockIdx.x;
  const int* __restrict__ idrow = ids + (size_t)b * NN;

  if (tid < CC) lcnt[tid] = 0.f;
  lcid[tid]       = idrow[row0 + tid];
  lcid[tid + 512] = idrow[row0 + tid + 512];
  {
    const float4 z4 = make_float4(0.f, 0.f, 0.f, 0.f);
#pragma unroll
    for (int i = 0; i < 16; ++i)
      *reinterpret_cast<float4*>(&slab[w][(i * 64 + lane) * 4]) = z4;
  }
  __syncthreads();
  atomicAdd(&lcnt[lcid[tid]], 1.f);
  atomicAdd(&lcnt[lcid[tid + 512]], 1.f);

  // wave w, group g (16 rows), instr k (2 rows): row = w*128+g*16+k*2+pr
  const float4* __restrict__ x4 = reinterpret_cast<const float4*>(
      x + ((size_t)b * NN + row0) * DD);
  const int wbase = w * 128;
  float* const sl = &slab[w][0];

  float4 vA[8], vB[8];
  int cA[8], cB[8];

#define LOADG(V, C, g)                                                     \
  {                                                                        \
    _Pragma("unroll") for (int k = 0; k < 8; ++k) {                        \
      const int rl = wbase + (g) * 16 + k * 2 + pr;                        \
      V[k] = x4[(size_t)rl * 32 + m];                                      \
      C[k] = lcid[rl];                                                     \
    }                                                                      \
  }
#define RMWG(V, C)                                                         \
  {                                                                        \
    _Pragma("unroll") for (int k = 0; k < 8; ++k) {                        \
      float* p = &sl[C[k] * DD + m];                                       \
      p[0]  += V[k].x;                                                     \
      p[32] += V[k].y;                                                     \
      p[64] += V[k].z;                                                     \
      p[96] += V[k].w;                                                     \
    }                                                                      \
  }

  LOADG(vA, cA, 0)                        // 8 groups of 16 rows, ping-pong
#pragma unroll
  for (int i = 0; i < 3; ++i) {
    LOADG(vB, cB, 2 * i + 1)
    RMWG(vA, cA)
    LOADG(vA, cA, 2 * i + 2)
    RMWG(vB, cB)
  }
  LOADG(vB, cB, 7)
  RMWG(vA, cA)                            // group 6
  RMWG(vB, cB)                            // group 7
#undef LOADG
#undef RMWG
  __syncthreads();

  // epilogue: fold 8 wave-slabs (permuted d-order kept — gram-invariant)
  float* __restrict__ ps = outsums + (size_t)slot * CC * DD;
#pragma unroll
  for (int it = 0; it < 8; ++it) {
    const int idx = it * 512 + tid;
    float s = slab[0][idx] + slab[1][idx] + slab[2][idx] + slab[3][idx] +
              slab[4][idx] + slab[5][idx] + slab[6][idx] + slab[7][idx];
    ps[idx] = s;
  }
  if (tid < CC) outcnts[slot * CC + tid] = lcnt[tid];
  if (slot == 0 && tid == 0)
    __hip_atomic_store(gctr, 0, __ATOMIC_RELAXED, __HIP_MEMORY_SCOPE_AGENT);
}

// ---------------- Kernel 2: fused reduce + gram + final (proven) ------------
#define MSTR 132
__global__ __launch_bounds__(512) void finish_fused_kernel(
    const float* __restrict__ psums, const float* __restrict__ pcnts,
    float* __restrict__ lossp, int* __restrict__ gctr,
    float* __restrict__ out) {
  __shared__ float mean[CC * MSTR];
  __shared__ float cnt[CC];
  __shared__ float red[512];

  const int b = blockIdx.x;
  const int tid = threadIdx.x;

  if (tid < CC) {
    float cs = 0.f;
#pragma unroll
    for (int c = 0; c < CHUNKS; ++c) cs += pcnts[(b * CHUNKS + c) * CC + tid];
    cnt[tid] = cs;
  }

  float4 a0 = make_float4(0.f, 0.f, 0.f, 0.f), a1 = a0;
  const size_t base = (size_t)b * CHUNKS * CC * DD + (size_t)tid * 8;
#pragma unroll 4
  for (int c = 0; c < CHUNKS; ++c) {
    const float4* p = reinterpret_cast<const float4*>(&psums[base + (size_t)c * CC * DD]);
    float4 q0 = p[0], q1 = p[1];
    a0.x += q0.x; a0.y += q0.y; a0.z += q0.z; a0.w += q0.w;
    a1.x += q1.x; a1.y += q1.y; a1.z += q1.z; a1.w += q1.w;
  }
  __syncthreads();

  {
    const int c = tid >> 4;
    const int d0 = (tid & 15) * 8;
    const float inv = 1.f / fmaxf(cnt[c], 1.f);
    float* mrow = &mean[c * MSTR + d0];
    mrow[0] = a0.x * inv; mrow[1] = a0.y * inv; mrow[2] = a0.z * inv; mrow[3] = a0.w * inv;
    mrow[4] = a1.x * inv; mrow[5] = a1.y * inv; mrow[6] = a1.z * inv; mrow[7] = a1.w * inv;
  }
  __syncthreads();

  float acc = 0.f;
  if (tid < (CC * (CC - 1)) / 2) {
    int c = 0, rem = tid;
    while (rem >= (CC - 1 - c)) { rem -= (CC - 1 - c); ++c; }
    int e = c + 1 + rem;
    const float4* mc = reinterpret_cast<const float4*>(&mean[c * MSTR]);
    const float4* me = reinterpret_cast<const float4*>(&mean[e * MSTR]);
    float dot = 0.f;
#pragma unroll 8
    for (int j = 0; j < DD / 4; ++j) {
      float4 u = mc[j], v = me[j];
      dot += u.x * v.x + u.y * v.y + u.z * v.z + u.w * v.w;
    }
    acc = fabsf(dot);
  }

  red[tid] = acc;
  __syncthreads();
  for (int s = 256; s > 0; s >>= 1) {
    if (tid < s) red[tid] += red[tid + s];
    __syncthreads();
  }

  if (tid == 0) {
    float valid = 0.f;
    for (int c = 0; c < CC; ++c) valid += (cnt[c] > 0.f) ? 1.f : 0.f;
    float denom = (valid > 1.f) ? valid * (valid - 1.f) * 0.5f : 1.f;
    float v = red[0] / denom * (1.0f / BB);
    __hip_atomic_store(&lossp[b], v, __ATOMIC_RELAXED, __HIP_MEMORY_SCOPE_AGENT);
    __threadfence();
    int old = __hip_atomic_fetch_add(gctr, 1, __ATOMIC_ACQ_REL,
                                     __HIP_MEMORY_SCOPE_AGENT);
    if (old == BB - 1) {
      __threadfence();
      float s = 0.f;
#pragma unroll
      for (int i = 0; i < BB; ++i)
        s += __hip_atomic_load(&lossp[i], __ATOMIC_RELAXED,
                               __HIP_MEMORY_SCOPE_AGENT);
      out[0] = s;
    }
  }
}

// ---------------- PATH B fallback (atomic accumulate) -----------------------
#define RPB_B 512
#define ROWS_PER_WAVE_B 128
__global__ __launch_bounds__(256) void seg_sum_rmw_b(
    const float* __restrict__ x, const int* __restrict__ ids,
    float* __restrict__ gsums, float* __restrict__ gcounts) {
  __shared__ float lsum[4][CC * DD];
  __shared__ float lcnt[CC];
  __shared__ int   lcid[RPB_B];

  const int tid  = threadIdx.x;
  const int b    = blockIdx.y;
  const int row0 = blockIdx.x * RPB_B;
  const int lane = tid & 63;
  const int w    = tid >> 6;
  const int* __restrict__ idrow = ids + (size_t)b * NN;

  if (tid < CC) lcnt[tid] = 0.f;
  lcid[tid]       = idrow[row0 + tid];
  lcid[tid + 256] = idrow[row0 + tid + 256];
  {
    const float4 z4 = make_float4(0.f, 0.f, 0.f, 0.f);
#pragma unroll
    for (int i = 0; i < 16; ++i)
      *reinterpret_cast<float4*>(&lsum[w][(i * 64 + lane) * 4]) = z4;
  }
  __syncthreads();
  atomicAdd(&lcnt[lcid[tid]], 1.f);
  atomicAdd(&lcnt[lcid[tid + 256]], 1.f);

  const float2* __restrict__ x2 =
      reinterpret_cast<const float2*>(x + (size_t)b * NN * DD);
  const int wbase = w * ROWS_PER_WAVE_B;
  float* const slab = &lsum[w][0];

  for (int g = 0; g < ROWS_PER_WAVE_B / 8; ++g) {
    float2 v[8]; int cid[8];
#pragma unroll
    for (int k = 0; k < 8; ++k) {
      const int rl = wbase + g * 8 + k;
      v[k]   = x2[(size_t)(row0 + rl) * 64 + lane];
      cid[k] = lcid[rl];
    }
#pragma unroll
    for (int k = 0; k < 8; ++k) {
      float2* p = reinterpret_cast<float2*>(&slab[cid[k] * DD + 2 * lane]);
      float2 old = *p;
      *p = make_float2(old.x + v[k].x, old.y + v[k].y);
    }
  }
  __syncthreads();

  float* __restrict__ gs = gsums + (size_t)b * CC * DD;
  for (int i = tid; i < CC * DD; i += 256) {
    float s = lsum[0][i] + lsum[1][i] + lsum[2][i] + lsum[3][i];
    atomicAdd(&gs[i], s);
  }
  if (tid < CC) atomicAdd(&gcounts[b * CC + tid], lcnt[tid]);
}

__global__ __launch_bounds__(512) void finish_kernel_b(
    const float* __restrict__ gsums, const float* __restrict__ gcounts,
    float* __restrict__ out) {
  __shared__ float mean[CC * MSTR];
  __shared__ float cnt[CC];
  __shared__ float red[512];

  const int b = blockIdx.x;
  const int tid = threadIdx.x;

  if (tid < CC) cnt[tid] = gcounts[b * CC + tid];
  __syncthreads();
  for (int i = tid; i < CC * DD; i += 512) {
    int c = i >> 7;
    int d = i & 127;
    mean[c * MSTR + d] = gsums[(size_t)b * CC * DD + i] / fmaxf(cnt[c], 1.f);
  }
  __syncthreads();

  float acc = 0.f;
  if (tid < (CC * (CC - 1)) / 2) {
    int c = 0, rem = tid;
    while (rem >= (CC - 1 - c)) { rem -= (CC - 1 - c); ++c; }
    int e = c + 1 + rem;
    const float4* mc = reinterpret_cast<const float4*>(&mean[c * MSTR]);
    const float4* me = reinterpret_cast<const float4*>(&mean[e * MSTR]);
    float dot = 0.f;
#pragma unroll 8
    for (int jj = 0; jj < DD / 4; ++jj) {
      float4 u = mc[jj], v = me[jj];
      dot += u.x * v.x + u.y * v.y + u.z * v.z + u.w * v.w;
    }
    acc = fabsf(dot);
  }
  red[tid] = acc;
  __syncthreads();
  for (int s = 256; s > 0; s >>= 1) {
    if (tid < s) red[tid] += red[tid + s];
    __syncthreads();
  }
  if (tid == 0) {
    float valid = 0.f;
    for (int c = 0; c < CC; ++c) valid += (cnt[c] > 0.f) ? 1.f : 0.f;
    float denom = (valid > 1.f) ? valid * (valid - 1.f) * 0.5f : 1.f;
    atomicAdd(out, red[0] / denom * (1.0f / BB));
  }
}

extern "C" void kernel_launch(void* const* d_in, const int* in_sizes, int n_in,
                              void* d_out, int out_size, void* d_ws, size_t ws_size,
                              hipStream_t stream) {
  const float* x   = (const float*)d_in[0];
  const int*   ids = (const int*)d_in[1];
  float* out = (float*)d_out;
  float* ws  = (float*)d_ws;

  if (ws_size >= WS_A_FLOATS * sizeof(float)) {
    float* psums = ws + P_SUMS;
    float* pcnts = ws + P_CNTS;
    float* lossp = ws + LOSSP;
    int*   gctr  = (int*)(ws + GCTR);
    dim3 grid1(CHUNKS, BB);
    seg_sum_kernel<<<grid1, 512, 0, stream>>>(x, ids, psums, pcnts, gctr);
    finish_fused_kernel<<<BB, 512, 0, stream>>>(psums, pcnts, lossp, gctr, out);
  } else {
    float* gsums   = ws;
    float* gcounts = gsums + (size_t)BB * CC * DD;
    const size_t wsb = ((size_t)BB * CC * DD + (size_t)BB * CC) * sizeof(float);
    hipMemsetAsync(d_ws, 0, wsb, stream);
    hipMemsetAsync(d_out, 0, sizeof(float), stream);
    dim3 gridb(NN / RPB_B, BB);
    seg_sum_rmw_b<<<gridb, 256, 0, stream>>>(x, ids, gsums, gcounts);
    finish_kernel_b<<<BB, 512, 0, stream>>>(gsums, gcounts, out);
  }
}